// Round 1
// baseline (394.843 us; speedup 1.0000x reference)
//
#include <hip/hip_runtime.h>
#include <hip/hip_bf16.h>

typedef __attribute__((ext_vector_type(8))) short bf16x8;
typedef __attribute__((ext_vector_type(4))) float f32x4;

#define NPIX 8192      // 8 * 32 * 32
#define HIDC 512
#define CIN  2048

// ---------- helpers ----------
__device__ __forceinline__ ushort f2b(float f) {
    union { float f; unsigned u; } v; v.f = f;
    unsigned r = v.u + 0x7fffu + ((v.u >> 16) & 1u);   // RNE
    return (ushort)(r >> 16);
}

__device__ __forceinline__ void gload16(const void* g, void* l) {
    __builtin_amdgcn_global_load_lds(
        (const __attribute__((address_space(1))) void*)g,
        (__attribute__((address_space(3))) void*)l, 16, 0, 0);
}

// ---------- 0: zero padded input buffer ----------
__global__ void zero_ws(uint4* __restrict__ p, int n16) {
    int i = blockIdx.x * blockDim.x + threadIdx.x;
    int stride = gridDim.x * blockDim.x;
    uint4 z = {0u, 0u, 0u, 0u};
    for (; i < n16; i += stride) p[i] = z;
}

// ---------- 1: NCHW fp32 -> padded NHWC bf16  xp[b][y+1][x+1][c] ----------
__global__ void pack_x(const float* __restrict__ x, ushort* __restrict__ xp) {
    __shared__ float tile[64][65];
    int b  = blockIdx.z;
    int c0 = blockIdx.y * 64;
    int p0 = blockIdx.x * 64;
    int t = threadIdx.x;
    int tx = t & 63, ty = t >> 6;
    const float* src = x + ((size_t)b * CIN + c0) * 1024 + p0;
    for (int i = ty; i < 64; i += 4)
        tile[i][tx] = src[(size_t)i * 1024 + tx];
    __syncthreads();
    int ci = t & 63, pj = t >> 6;
    for (int j = pj; j < 64; j += 4) {
        int p = p0 + j;
        int y = p >> 5, xx = p & 31;
        ushort* dst = xp + (((size_t)b * 34 + y + 1) * 34 + (xx + 1)) * CIN + c0;
        dst[ci] = f2b(tile[ci][j]);
    }
}

// ---------- 2: w[n][c][ky][kx] fp32 -> wpk[tap][n][c] bf16 ----------
__global__ void pack_w(const float* __restrict__ hw, ushort* __restrict__ wpk) {
    __shared__ float ld[512 * 9];
    int n = blockIdx.x;
    int t = threadIdx.x;
    const float* src = hw + (size_t)n * (CIN * 9);
    for (int cc0 = 0; cc0 < CIN; cc0 += 512) {
        for (int i = t; i < 4608; i += 256) ld[i] = src[(size_t)cc0 * 9 + i];
        __syncthreads();
        for (int t9 = 0; t9 < 9; ++t9)
            for (int idx = t; idx < 512; idx += 256)
                wpk[((size_t)(t9 * 512 + n)) * CIN + cc0 + idx] = f2b(ld[idx * 9 + t9]);
        __syncthreads();
    }
}

// ---------- 3: conf_w/reg_w -> w2b[48][512] bf16 (rows 45..47 zero) ----------
__global__ void pack_w2(const float* __restrict__ cw, const float* __restrict__ rw,
                        ushort* __restrict__ w2b) {
    int i = blockIdx.x * 256 + threadIdx.x;
    if (i >= 48 * 512) return;
    int m = i >> 9, c = i & 511;
    float v = 0.f;
    if (m < 9) v = cw[m * 512 + c];
    else if (m < 45) v = rw[(m - 9) * 512 + c];
    w2b[i] = f2b(v);
}

// ---------- 4: implicit-GEMM 3x3 conv, bias+ReLU -> hidden bf16 [8192][512] ----------
__launch_bounds__(256, 1)
__global__ void conv_gemm(const ushort* __restrict__ xp, const ushort* __restrict__ wpk,
                          const float* __restrict__ hb, ushort* __restrict__ hidden) {
    __shared__ __align__(16) ushort Al[128 * 32];
    __shared__ __align__(16) ushort Bl[128 * 32];
    int t = threadIdx.x;
    int n0   = blockIdx.x * 128;
    int pix0 = blockIdx.y * 128;
    int w = t >> 6, l = t & 63;
    int wr = w >> 1, wc = w & 1;

    int rA = t >> 2;            // 0..63
    int kA = (t & 3) * 8;       // 0,8,16,24
    int p1 = pix0 + rA, p2 = p1 + 64;
    int b   = p1 >> 10;
    int py1 = (p1 >> 5) & 31, px1 = p1 & 31;
    int py2 = (p2 >> 5) & 31, px2 = p2 & 31;

    f32x4 zero = {0.f, 0.f, 0.f, 0.f};
    f32x4 acc[4][4];
#pragma unroll
    for (int i = 0; i < 4; ++i)
#pragma unroll
        for (int j = 0; j < 4; ++j) acc[i][j] = zero;

    char* ldsA1 = (char*)&Al[0] + t * 16;
    char* ldsA2 = (char*)&Al[0] + 4096 + t * 16;
    char* ldsB1 = (char*)&Bl[0] + t * 16;
    char* ldsB2 = (char*)&Bl[0] + 4096 + t * 16;

    int lr = l & 15;
    int lk = (l >> 4) * 8;

    for (int tap = 0; tap < 9; ++tap) {
        int dy = tap / 3, dx = tap % 3;
        const ushort* a1  = xp + (((size_t)b * 34 + py1 + dy) * 34 + (px1 + dx)) * CIN + kA;
        const ushort* a2  = xp + (((size_t)b * 34 + py2 + dy) * 34 + (px2 + dx)) * CIN + kA;
        const ushort* bs1 = wpk + ((size_t)(tap * 512) + n0 + rA) * CIN + kA;
        const ushort* bs2 = bs1 + (size_t)64 * CIN;
        for (int c0 = 0; c0 < CIN; c0 += 32) {
            gload16(a1 + c0, ldsA1);
            gload16(a2 + c0, ldsA2);
            gload16(bs1 + c0, ldsB1);
            gload16(bs2 + c0, ldsB2);
            __syncthreads();
            bf16x8 af[4], bfr[4];
#pragma unroll
            for (int mi = 0; mi < 4; ++mi)
                af[mi] = *(const bf16x8*)&Al[(wr * 64 + mi * 16 + lr) * 32 + lk];
#pragma unroll
            for (int ni = 0; ni < 4; ++ni)
                bfr[ni] = *(const bf16x8*)&Bl[(wc * 64 + ni * 16 + lr) * 32 + lk];
#pragma unroll
            for (int mi = 0; mi < 4; ++mi)
#pragma unroll
                for (int ni = 0; ni < 4; ++ni)
                    acc[mi][ni] = __builtin_amdgcn_mfma_f32_16x16x32_bf16(
                        af[mi], bfr[ni], acc[mi][ni], 0, 0, 0);
            __syncthreads();
        }
    }

    int lr4 = (l >> 4) * 4;
#pragma unroll
    for (int mi = 0; mi < 4; ++mi) {
#pragma unroll
        for (int ni = 0; ni < 4; ++ni) {
            int col = n0 + wc * 64 + ni * 16 + lr;
            float bias = hb[col];
#pragma unroll
            for (int r = 0; r < 4; ++r) {
                int row = pix0 + wr * 64 + mi * 16 + lr4 + r;
                float v = acc[mi][ni][r] + bias;
                v = v > 0.f ? v : 0.f;
                hidden[(size_t)row * HIDC + col] = f2b(v);
            }
        }
    }
}

// ---------- 5: 1x1 convs as GEMM (N=48 incl pad), bias -> g fp32 [8192][48] ----------
__launch_bounds__(256)
__global__ void gemm2(const ushort* __restrict__ hidden, const ushort* __restrict__ w2b,
                      const float* __restrict__ cb, const float* __restrict__ rb,
                      float* __restrict__ g) {
    __shared__ __align__(16) ushort W2[48 * 520];
    int t = threadIdx.x;
    const unsigned* src = (const unsigned*)w2b;
    unsigned* dstW = (unsigned*)&W2[0];
    for (int i = t; i < 12288; i += 256) {
        int m = i >> 8, c2 = i & 255;
        dstW[m * 260 + c2] = src[i];
    }
    __syncthreads();
    int w = t >> 6, l = t & 63;
    int p0 = blockIdx.x * 64 + w * 16;
    int lr = l & 15, lk = (l >> 4) * 8;
    f32x4 zero = {0.f, 0.f, 0.f, 0.f};
    f32x4 acc[3] = {zero, zero, zero};
    const ushort* hrow = hidden + (size_t)(p0 + lr) * HIDC + lk;
#pragma unroll 4
    for (int k0 = 0; k0 < 16; ++k0) {
        bf16x8 a = *(const bf16x8*)(hrow + k0 * 32);
#pragma unroll
        for (int ni = 0; ni < 3; ++ni) {
            bf16x8 bb = *(const bf16x8*)&W2[(ni * 16 + lr) * 520 + k0 * 32 + lk];
            acc[ni] = __builtin_amdgcn_mfma_f32_16x16x32_bf16(a, bb, acc[ni], 0, 0, 0);
        }
    }
    int lr4 = (l >> 4) * 4;
#pragma unroll
    for (int ni = 0; ni < 3; ++ni) {
        int m = ni * 16 + lr;
        float bias = (m < 9) ? cb[m] : ((m < 45) ? rb[m - 9] : 0.f);
#pragma unroll
        for (int r = 0; r < 4; ++r) {
            int p = p0 + lr4 + r;
            g[(size_t)p * 48 + m] = acc[ni][r] + bias;
        }
    }
}

// ---------- 6: proposal math ----------
__global__ void proposals(const float* __restrict__ g, float* __restrict__ out) {
    int i = blockIdx.x * 256 + threadIdx.x;
    if (i >= NPIX * 9) return;
    int p = i / 9, a = i - p * 9;
    int y = (p >> 5) & 31, x = p & 31;
    int si = a / 3, ri = a - si * 3;
    float hA = 2.f * (float)(si + 1);
    float wA = (float)((si + 1) * (ri + 1));

    const float* gp = g + (size_t)p * 48;
    float conf = gp[a];
    float o0 = gp[9 + a * 4 + 0];
    float o1 = gp[9 + a * 4 + 1];
    float o2 = gp[9 + a * 4 + 2];
    float o3 = gp[9 + a * 4 + 3];

    float cx = x + 0.5f, cy = y + 0.5f;
    float x1 = fminf(fmaxf(cx - wA * 0.5f, 0.f), 32.f);
    float y1 = fminf(fmaxf(cy - hA * 0.5f, 0.f), 32.f);
    float x2 = fminf(fmaxf(cx + wA * 0.5f, 0.f), 32.f);
    float y2 = fminf(fmaxf(cy + hA * 0.5f, 0.f), 32.f);
    float aw = x2 - x1, ah = y2 - y1;
    float acx = x1 + aw * 0.5f, acy = y1 + ah * 0.5f;
    float pcx = acx + o0 * aw, pcy = acy + o1 * ah;
    float pw = aw * expf(o2), ph = ah * expf(o3);
    float s = 1.f / (1.f + expf(-conf));

    float* o = out + (size_t)i * 5;
    o[0] = s;
    o[1] = (pcx - pw * 0.5f) * 32.f;
    o[2] = (pcy - ph * 0.5f) * 32.f;
    o[3] = (pcx + pw * 0.5f) * 32.f;
    o[4] = (pcy + ph * 0.5f) * 32.f;
}

extern "C" void kernel_launch(void* const* d_in, const int* in_sizes, int n_in,
                              void* d_out, int out_size, void* d_ws, size_t ws_size,
                              hipStream_t stream) {
    const float* x  = (const float*)d_in[0];
    const float* hw = (const float*)d_in[1];
    const float* hb = (const float*)d_in[2];
    const float* cw = (const float*)d_in[3];
    const float* cb = (const float*)d_in[4];
    const float* rw = (const float*)d_in[5];
    const float* rb = (const float*)d_in[6];
    float* out = (float*)d_out;

    char* ws = (char*)d_ws;
    ushort* xp     = (ushort*)(ws);                 // 8*34*34*2048*2  = 37,879,808
    ushort* wpk    = (ushort*)(ws + 37879808);      // 9*512*2048*2   = 18,874,368
    ushort* hidden = (ushort*)(ws + 56754176);      // 8192*512*2     =  8,388,608
    ushort* w2b    = (ushort*)(ws + 65142784);      // 48*512*2       =     49,152
    float*  g      = (float*)(ws + 65191936);       // 8192*48*4      =  1,572,864

    hipLaunchKernelGGL(zero_ws, dim3(2048), dim3(256), 0, stream,
                       (uint4*)xp, 37879808 / 16);
    hipLaunchKernelGGL(pack_x, dim3(16, 32, 8), dim3(256), 0, stream, x, xp);
    hipLaunchKernelGGL(pack_w, dim3(512), dim3(256), 0, stream, hw, wpk);
    hipLaunchKernelGGL(pack_w2, dim3(96), dim3(256), 0, stream, cw, rw, w2b);
    hipLaunchKernelGGL(conv_gemm, dim3(4, 64), dim3(256), 0, stream, xp, wpk, hb, hidden);
    hipLaunchKernelGGL(gemm2, dim3(128), dim3(256), 0, stream, hidden, w2b, cb, rb, g);
    hipLaunchKernelGGL(proposals, dim3(288), dim3(256), 0, stream, g, out);
}

// Round 2
// 372.220 us; speedup vs baseline: 1.0608x; 1.0608x over previous
//
#include <hip/hip_runtime.h>
#include <hip/hip_bf16.h>

typedef __attribute__((ext_vector_type(8))) short bf16x8;
typedef __attribute__((ext_vector_type(4))) float f32x4;

#define NPIX 8192      // 8 * 32 * 32
#define HIDC 512
#define CIN  2048

// ---------- helpers ----------
__device__ __forceinline__ ushort f2b(float f) {
    union { float f; unsigned u; } v; v.f = f;
    unsigned r = v.u + 0x7fffu + ((v.u >> 16) & 1u);   // RNE
    return (ushort)(r >> 16);
}

__device__ __forceinline__ void gload16(const void* g, void* l) {
    __builtin_amdgcn_global_load_lds(
        (const __attribute__((address_space(1))) void*)g,
        (__attribute__((address_space(3))) void*)l, 16, 0, 0);
}

// ---------- 0: zero padded input buffer ----------
__global__ void zero_ws(uint4* __restrict__ p, int n16) {
    int i = blockIdx.x * blockDim.x + threadIdx.x;
    int stride = gridDim.x * blockDim.x;
    uint4 z = {0u, 0u, 0u, 0u};
    for (; i < n16; i += stride) p[i] = z;
}

// ---------- 1: NCHW fp32 -> padded NHWC bf16  xp[b][y+1][x+1][c] ----------
__global__ void pack_x(const float* __restrict__ x, ushort* __restrict__ xp) {
    __shared__ float tile[64][65];
    int b  = blockIdx.z;
    int c0 = blockIdx.y * 64;
    int p0 = blockIdx.x * 64;
    int t = threadIdx.x;
    int tx = t & 63, ty = t >> 6;
    const float* src = x + ((size_t)b * CIN + c0) * 1024 + p0;
    for (int i = ty; i < 64; i += 4)
        tile[i][tx] = src[(size_t)i * 1024 + tx];
    __syncthreads();
    int ci = t & 63, pj = t >> 6;
    for (int j = pj; j < 64; j += 4) {
        int p = p0 + j;
        int y = p >> 5, xx = p & 31;
        ushort* dst = xp + (((size_t)b * 34 + y + 1) * 34 + (xx + 1)) * CIN + c0;
        dst[ci] = f2b(tile[ci][j]);
    }
}

// ---------- 2: w[n][c][ky][kx] fp32 -> wpk[tap][n][c] bf16 ----------
__global__ void pack_w(const float* __restrict__ hw, ushort* __restrict__ wpk) {
    __shared__ float ld[512 * 9];
    int n = blockIdx.x;
    int t = threadIdx.x;
    const float* src = hw + (size_t)n * (CIN * 9);
    for (int cc0 = 0; cc0 < CIN; cc0 += 512) {
        for (int i = t; i < 4608; i += 256) ld[i] = src[(size_t)cc0 * 9 + i];
        __syncthreads();
        for (int t9 = 0; t9 < 9; ++t9)
            for (int idx = t; idx < 512; idx += 256)
                wpk[((size_t)(t9 * 512 + n)) * CIN + cc0 + idx] = f2b(ld[idx * 9 + t9]);
        __syncthreads();
    }
}

// ---------- 3: conf_w/reg_w -> w2b[48][512] bf16 (rows 45..47 zero) ----------
__global__ void pack_w2(const float* __restrict__ cw, const float* __restrict__ rw,
                        ushort* __restrict__ w2b) {
    int i = blockIdx.x * 256 + threadIdx.x;
    if (i >= 48 * 512) return;
    int m = i >> 9, c = i & 511;
    float v = 0.f;
    if (m < 9) v = cw[m * 512 + c];
    else if (m < 45) v = rw[(m - 9) * 512 + c];
    w2b[i] = f2b(v);
}

// ---------- 4: implicit-GEMM 3x3 conv, 2-phase dbuf prefetch ----------
#define NKSTEP 576   // 9 taps * 64 (2048/32)

__launch_bounds__(256, 1)
__global__ void conv_gemm(const ushort* __restrict__ xp, const ushort* __restrict__ wpk,
                          const float* __restrict__ hb, ushort* __restrict__ hidden) {
    // 4 SEPARATE shared arrays: keeps alias analysis from inserting vmcnt
    // waits between prefetch (into buf1) and ds_read (from buf0).
    __shared__ __align__(16) ushort A0[128 * 32];
    __shared__ __align__(16) ushort B0[128 * 32];
    __shared__ __align__(16) ushort A1[128 * 32];
    __shared__ __align__(16) ushort B1[128 * 32];

    int t = threadIdx.x;

    // chunked XCD swizzle: 256 blocks, 8 XCDs, 32 blocks/XCD.
    // siblings (4 n-blocks of one pixel-block) land on the same XCD.
    int orig = blockIdx.x;
    int xcd = orig & 7;
    int ix  = orig >> 3;            // 0..31, stays within one XCD round-robin slot
    int nb  = ix & 3;               // n-block 0..3
    int pb  = (xcd << 3) + (ix >> 2);  // pixel-block 0..63
    int n0   = nb * 128;
    int pix0 = pb * 128;

    int w = t >> 6, l = t & 63;
    int wr = w >> 1, wc = w & 1;

    int rA = t >> 2;            // 0..63
    int kA = (t & 3) * 8;       // 0,8,16,24 (elements)
    int p1 = pix0 + rA, p2 = p1 + 64;
    int b   = p1 >> 10;
    int py1 = (p1 >> 5) & 31, px1 = p1 & 31;
    int py2 = (p2 >> 5) & 31, px2 = p2 & 31;

    size_t aBase1 = ((size_t)b * 34 + py1) * 34 + px1;   // element-row index into xp
    size_t aBase2 = ((size_t)b * 34 + py2) * 34 + px2;

    f32x4 zero = {0.f, 0.f, 0.f, 0.f};
    f32x4 acc[4][4];
#pragma unroll
    for (int i = 0; i < 4; ++i)
#pragma unroll
        for (int j = 0; j < 4; ++j) acc[i][j] = zero;

    int lr = l & 15;
    int lk = (l >> 4) * 8;

    auto stage = [&](int kk, ushort* As, ushort* Bs) {
        int tap = kk >> 6;
        int c0 = (kk & 63) << 5;
        int dy = tap / 3, dx = tap - dy * 3;
        size_t aoff = (size_t)(dy * 34 + dx) * CIN + kA + c0;
        gload16(xp + aBase1 * CIN + aoff, (char*)As + t * 16);
        gload16(xp + aBase2 * CIN + aoff, (char*)As + 4096 + t * 16);
        const ushort* bp = wpk + ((size_t)(tap * 512) + n0 + rA) * CIN + kA + c0;
        gload16(bp, (char*)Bs + t * 16);
        gload16(bp + (size_t)64 * CIN, (char*)Bs + 4096 + t * 16);
    };

    auto compute = [&](const ushort* As, const ushort* Bs) {
        bf16x8 af[4], bfr[4];
#pragma unroll
        for (int mi = 0; mi < 4; ++mi)
            af[mi] = *(const bf16x8*)&As[(wr * 64 + mi * 16 + lr) * 32 + lk];
#pragma unroll
        for (int ni = 0; ni < 4; ++ni)
            bfr[ni] = *(const bf16x8*)&Bs[(wc * 64 + ni * 16 + lr) * 32 + lk];
#pragma unroll
        for (int mi = 0; mi < 4; ++mi)
#pragma unroll
            for (int ni = 0; ni < 4; ++ni)
                acc[mi][ni] = __builtin_amdgcn_mfma_f32_16x16x32_bf16(
                    af[mi], bfr[ni], acc[mi][ni], 0, 0, 0);
    };

    stage(0, A0, B0);
    __syncthreads();                 // drains vmcnt(0): buf0 ready
    for (int kk = 0; kk < NKSTEP; kk += 2) {
        if (kk + 1 < NKSTEP) stage(kk + 1, A1, B1);   // prefetch overlaps compute
        compute(A0, B0);
        __syncthreads();             // drain prefetch + release buf0
        if (kk + 2 < NKSTEP) stage(kk + 2, A0, B0);
        compute(A1, B1);
        __syncthreads();
    }

    int lr4 = (l >> 4) * 4;
#pragma unroll
    for (int mi = 0; mi < 4; ++mi) {
#pragma unroll
        for (int ni = 0; ni < 4; ++ni) {
            int col = n0 + wc * 64 + ni * 16 + lr;
            float bias = hb[col];
#pragma unroll
            for (int r = 0; r < 4; ++r) {
                int row = pix0 + wr * 64 + mi * 16 + lr4 + r;
                float v = acc[mi][ni][r] + bias;
                v = v > 0.f ? v : 0.f;
                hidden[(size_t)row * HIDC + col] = f2b(v);
            }
        }
    }
}

// ---------- 5: 1x1 convs as GEMM (N=48 incl pad), bias -> g fp32 [8192][48] ----------
__launch_bounds__(256)
__global__ void gemm2(const ushort* __restrict__ hidden, const ushort* __restrict__ w2b,
                      const float* __restrict__ cb, const float* __restrict__ rb,
                      float* __restrict__ g) {
    __shared__ __align__(16) ushort W2[48 * 520];
    int t = threadIdx.x;
    const unsigned* src = (const unsigned*)w2b;
    unsigned* dstW = (unsigned*)&W2[0];
    for (int i = t; i < 12288; i += 256) {
        int m = i >> 8, c2 = i & 255;
        dstW[m * 260 + c2] = src[i];
    }
    __syncthreads();
    int w = t >> 6, l = t & 63;
    int p0 = blockIdx.x * 64 + w * 16;
    int lr = l & 15, lk = (l >> 4) * 8;
    f32x4 zero = {0.f, 0.f, 0.f, 0.f};
    f32x4 acc[3] = {zero, zero, zero};
    const ushort* hrow = hidden + (size_t)(p0 + lr) * HIDC + lk;
#pragma unroll 4
    for (int k0 = 0; k0 < 16; ++k0) {
        bf16x8 a = *(const bf16x8*)(hrow + k0 * 32);
#pragma unroll
        for (int ni = 0; ni < 3; ++ni) {
            bf16x8 bb = *(const bf16x8*)&W2[(ni * 16 + lr) * 520 + k0 * 32 + lk];
            acc[ni] = __builtin_amdgcn_mfma_f32_16x16x32_bf16(a, bb, acc[ni], 0, 0, 0);
        }
    }
    int lr4 = (l >> 4) * 4;
#pragma unroll
    for (int ni = 0; ni < 3; ++ni) {
        int m = ni * 16 + lr;
        float bias = (m < 9) ? cb[m] : ((m < 45) ? rb[m - 9] : 0.f);
#pragma unroll
        for (int r = 0; r < 4; ++r) {
            int p = p0 + lr4 + r;
            g[(size_t)p * 48 + m] = acc[ni][r] + bias;
        }
    }
}

// ---------- 6: proposal math ----------
__global__ void proposals(const float* __restrict__ g, float* __restrict__ out) {
    int i = blockIdx.x * 256 + threadIdx.x;
    if (i >= NPIX * 9) return;
    int p = i / 9, a = i - p * 9;
    int y = (p >> 5) & 31, x = p & 31;
    int si = a / 3, ri = a - si * 3;
    float hA = 2.f * (float)(si + 1);
    float wA = (float)((si + 1) * (ri + 1));

    const float* gp = g + (size_t)p * 48;
    float conf = gp[a];
    float o0 = gp[9 + a * 4 + 0];
    float o1 = gp[9 + a * 4 + 1];
    float o2 = gp[9 + a * 4 + 2];
    float o3 = gp[9 + a * 4 + 3];

    float cx = x + 0.5f, cy = y + 0.5f;
    float x1 = fminf(fmaxf(cx - wA * 0.5f, 0.f), 32.f);
    float y1 = fminf(fmaxf(cy - hA * 0.5f, 0.f), 32.f);
    float x2 = fminf(fmaxf(cx + wA * 0.5f, 0.f), 32.f);
    float y2 = fminf(fmaxf(cy + hA * 0.5f, 0.f), 32.f);
    float aw = x2 - x1, ah = y2 - y1;
    float acx = x1 + aw * 0.5f, acy = y1 + ah * 0.5f;
    float pcx = acx + o0 * aw, pcy = acy + o1 * ah;
    float pw = aw * expf(o2), ph = ah * expf(o3);
    float s = 1.f / (1.f + expf(-conf));

    float* o = out + (size_t)i * 5;
    o[0] = s;
    o[1] = (pcx - pw * 0.5f) * 32.f;
    o[2] = (pcy - ph * 0.5f) * 32.f;
    o[3] = (pcx + pw * 0.5f) * 32.f;
    o[4] = (pcy + ph * 0.5f) * 32.f;
}

extern "C" void kernel_launch(void* const* d_in, const int* in_sizes, int n_in,
                              void* d_out, int out_size, void* d_ws, size_t ws_size,
                              hipStream_t stream) {
    const float* x  = (const float*)d_in[0];
    const float* hw = (const float*)d_in[1];
    const float* hb = (const float*)d_in[2];
    const float* cw = (const float*)d_in[3];
    const float* cb = (const float*)d_in[4];
    const float* rw = (const float*)d_in[5];
    const float* rb = (const float*)d_in[6];
    float* out = (float*)d_out;

    char* ws = (char*)d_ws;
    ushort* xp     = (ushort*)(ws);                 // 8*34*34*2048*2  = 37,879,808
    ushort* wpk    = (ushort*)(ws + 37879808);      // 9*512*2048*2   = 18,874,368
    ushort* hidden = (ushort*)(ws + 56754176);      // 8192*512*2     =  8,388,608
    ushort* w2b    = (ushort*)(ws + 65142784);      // 48*512*2       =     49,152
    float*  g      = (float*)(ws + 65191936);       // 8192*48*4      =  1,572,864

    hipLaunchKernelGGL(zero_ws, dim3(2048), dim3(256), 0, stream,
                       (uint4*)xp, 37879808 / 16);
    hipLaunchKernelGGL(pack_x, dim3(16, 32, 8), dim3(256), 0, stream, x, xp);
    hipLaunchKernelGGL(pack_w, dim3(512), dim3(256), 0, stream, hw, wpk);
    hipLaunchKernelGGL(pack_w2, dim3(96), dim3(256), 0, stream, cw, rw, w2b);
    hipLaunchKernelGGL(conv_gemm, dim3(256), dim3(256), 0, stream, xp, wpk, hb, hidden);
    hipLaunchKernelGGL(gemm2, dim3(128), dim3(256), 0, stream, hidden, w2b, cb, rb, g);
    hipLaunchKernelGGL(proposals, dim3(288), dim3(256), 0, stream, g, out);
}

// Round 3
// 365.035 us; speedup vs baseline: 1.0817x; 1.0197x over previous
//
#include <hip/hip_runtime.h>
#include <hip/hip_bf16.h>

typedef __attribute__((ext_vector_type(8))) short bf16x8;
typedef __attribute__((ext_vector_type(4))) float f32x4;

#define NPIX 8192      // 8 * 32 * 32
#define HIDC 512
#define CIN  2048

// ---------- helpers ----------
__device__ __forceinline__ ushort f2b(float f) {
    union { float f; unsigned u; } v; v.f = f;
    unsigned r = v.u + 0x7fffu + ((v.u >> 16) & 1u);   // RNE
    return (ushort)(r >> 16);
}

__device__ __forceinline__ void gload16(const void* g, void* l) {
    __builtin_amdgcn_global_load_lds(
        (const __attribute__((address_space(1))) void*)g,
        (__attribute__((address_space(3))) void*)l, 16, 0, 0);
}

// ---------- 0: zero padded input buffer ----------
__global__ void zero_ws(uint4* __restrict__ p, int n16) {
    int i = blockIdx.x * blockDim.x + threadIdx.x;
    int stride = gridDim.x * blockDim.x;
    uint4 z = {0u, 0u, 0u, 0u};
    for (; i < n16; i += stride) p[i] = z;
}

// ---------- 1: NCHW fp32 -> padded NHWC bf16  xp[b][y+1][x+1][c] ----------
__global__ void pack_x(const float* __restrict__ x, ushort* __restrict__ xp) {
    __shared__ float tile[64][65];
    int b  = blockIdx.z;
    int c0 = blockIdx.y * 64;
    int p0 = blockIdx.x * 64;
    int t = threadIdx.x;
    int tx = t & 63, ty = t >> 6;
    const float* src = x + ((size_t)b * CIN + c0) * 1024 + p0;
    for (int i = ty; i < 64; i += 4)
        tile[i][tx] = src[(size_t)i * 1024 + tx];
    __syncthreads();
    int ci = t & 63, pj = t >> 6;
    for (int j = pj; j < 64; j += 4) {
        int p = p0 + j;
        int y = p >> 5, xx = p & 31;
        ushort* dst = xp + (((size_t)b * 34 + y + 1) * 34 + (xx + 1)) * CIN + c0;
        dst[ci] = f2b(tile[ci][j]);
    }
}

// ---------- 2: w[n][c][ky][kx] fp32 -> wpk[tap][n][c] bf16 ----------
__global__ void pack_w(const float* __restrict__ hw, ushort* __restrict__ wpk) {
    __shared__ float ld[512 * 9];
    int n = blockIdx.x;
    int t = threadIdx.x;
    const float* src = hw + (size_t)n * (CIN * 9);
    for (int cc0 = 0; cc0 < CIN; cc0 += 512) {
        for (int i = t; i < 4608; i += 256) ld[i] = src[(size_t)cc0 * 9 + i];
        __syncthreads();
        for (int t9 = 0; t9 < 9; ++t9)
            for (int idx = t; idx < 512; idx += 256)
                wpk[((size_t)(t9 * 512 + n)) * CIN + cc0 + idx] = f2b(ld[idx * 9 + t9]);
        __syncthreads();
    }
}

// ---------- 3: conf_w/reg_w -> w2b[48][512] bf16 (rows 45..47 zero) ----------
__global__ void pack_w2(const float* __restrict__ cw, const float* __restrict__ rw,
                        ushort* __restrict__ w2b) {
    int i = blockIdx.x * 256 + threadIdx.x;
    if (i >= 48 * 512) return;
    int m = i >> 9, c = i & 511;
    float v = 0.f;
    if (m < 9) v = cw[m * 512 + c];
    else if (m < 45) v = rw[(m - 9) * 512 + c];
    w2b[i] = f2b(v);
}

// ---------- 4: implicit-GEMM 3x3 conv, dbuf prefetch + XOR-swizzled LDS ----------
// LDS tile layout (per 64-row half, 256 slots of 16B): slot for (row r, 16B
// k-chunk kc) = (r*4 + kc) ^ ((r>>1)&7).  Bijective; staging dest stays
// LINEAR (slot t = thread t) and the SOURCE (r,kc) per thread is permuted
// with the inverse (same) XOR — rule #21.  Per quarter-wave (fixed kc,
// 16 consecutive rows) the slots hit all 8 bank-quads exactly 2x ->
// conflict-free ds_read_b128.
#define NKSTEP 576   // 9 taps * 64 (2048/32)

__launch_bounds__(256, 1)
__global__ void conv_gemm(const ushort* __restrict__ xp, const ushort* __restrict__ wpk,
                          const float* __restrict__ hb, ushort* __restrict__ hidden) {
    __shared__ __align__(16) ushort A0[128 * 32];
    __shared__ __align__(16) ushort B0[128 * 32];
    __shared__ __align__(16) ushort A1[128 * 32];
    __shared__ __align__(16) ushort B1[128 * 32];

    int t = threadIdx.x;

    // chunked XCD swizzle: 256 blocks, 8 XCDs; n-siblings share an XCD
    int orig = blockIdx.x;
    int xcd = orig & 7;
    int ix  = orig >> 3;
    int nb  = ix & 3;
    int pb  = (xcd << 3) + (ix >> 2);
    int n0   = nb * 128;
    int pix0 = pb * 128;

    int w = t >> 6, l = t & 63;
    int wr = w >> 1, wc = w & 1;

    // ---- staging-side inverse swizzle: LDS slot t holds (rA, kA) ----
    int u  = t ^ ((t >> 3) & 7);
    int rA = u >> 2;            // 0..63 (row within half-tile)
    int kA = (u & 3) * 8;       // element offset of 16B chunk

    int p1 = pix0 + rA, p2 = p1 + 64;
    int b   = p1 >> 10;
    int py1 = (p1 >> 5) & 31, px1 = p1 & 31;
    int py2 = (p2 >> 5) & 31, px2 = p2 & 31;

    size_t aBase1 = ((size_t)b * 34 + py1) * 34 + px1;
    size_t aBase2 = ((size_t)b * 34 + py2) * 34 + px2;

    f32x4 zero = {0.f, 0.f, 0.f, 0.f};
    f32x4 acc[4][4];
#pragma unroll
    for (int i = 0; i < 4; ++i)
#pragma unroll
        for (int j = 0; j < 4; ++j) acc[i][j] = zero;

    int lr = l & 15;
    int kc = l >> 4;            // 16B chunk index 0..3
    // read-side swizzled byte offset within each 1KB (16-row) sub-tile
    int sw = ((lr * 4 + kc) ^ ((lr >> 1) & 7)) * 16;

    auto stage = [&](int kk, ushort* As, ushort* Bs) {
        int tap = kk >> 6;
        int c0 = (kk & 63) << 5;
        int dy = tap / 3, dx = tap - dy * 3;
        size_t aoff = (size_t)(dy * 34 + dx) * CIN + kA + c0;
        gload16(xp + aBase1 * CIN + aoff, (char*)As + t * 16);
        gload16(xp + aBase2 * CIN + aoff, (char*)As + 4096 + t * 16);
        const ushort* bp = wpk + ((size_t)(tap * 512) + n0 + rA) * CIN + kA + c0;
        gload16(bp, (char*)Bs + t * 16);
        gload16(bp + (size_t)64 * CIN, (char*)Bs + 4096 + t * 16);
    };

    auto compute = [&](const ushort* As, const ushort* Bs) {
        const char* ab = (const char*)As + wr * 4096 + sw;
        const char* bb = (const char*)Bs + wc * 4096 + sw;
        bf16x8 af[4], bfr[4];
#pragma unroll
        for (int mi = 0; mi < 4; ++mi)
            af[mi] = *(const bf16x8*)(ab + mi * 1024);
#pragma unroll
        for (int ni = 0; ni < 4; ++ni)
            bfr[ni] = *(const bf16x8*)(bb + ni * 1024);
#pragma unroll
        for (int mi = 0; mi < 4; ++mi)
#pragma unroll
            for (int ni = 0; ni < 4; ++ni)
                acc[mi][ni] = __builtin_amdgcn_mfma_f32_16x16x32_bf16(
                    af[mi], bfr[ni], acc[mi][ni], 0, 0, 0);
    };

    stage(0, A0, B0);
    __syncthreads();
    for (int kk = 0; kk < NKSTEP; kk += 2) {
        if (kk + 1 < NKSTEP) stage(kk + 1, A1, B1);
        compute(A0, B0);
        __syncthreads();
        if (kk + 2 < NKSTEP) stage(kk + 2, A0, B0);
        compute(A1, B1);
        __syncthreads();
    }

    int lr4 = (l >> 4) * 4;
#pragma unroll
    for (int mi = 0; mi < 4; ++mi) {
#pragma unroll
        for (int ni = 0; ni < 4; ++ni) {
            int col = n0 + wc * 64 + ni * 16 + lr;
            float bias = hb[col];
#pragma unroll
            for (int r = 0; r < 4; ++r) {
                int row = pix0 + wr * 64 + mi * 16 + lr4 + r;
                float v = acc[mi][ni][r] + bias;
                v = v > 0.f ? v : 0.f;
                hidden[(size_t)row * HIDC + col] = f2b(v);
            }
        }
    }
}

// ---------- 5: 1x1 convs as GEMM (N=48 incl pad), bias -> g fp32 [8192][48] ----------
__launch_bounds__(256)
__global__ void gemm2(const ushort* __restrict__ hidden, const ushort* __restrict__ w2b,
                      const float* __restrict__ cb, const float* __restrict__ rb,
                      float* __restrict__ g) {
    __shared__ __align__(16) ushort W2[48 * 520];
    int t = threadIdx.x;
    const unsigned* src = (const unsigned*)w2b;
    unsigned* dstW = (unsigned*)&W2[0];
    for (int i = t; i < 12288; i += 256) {
        int m = i >> 8, c2 = i & 255;
        dstW[m * 260 + c2] = src[i];
    }
    __syncthreads();
    int w = t >> 6, l = t & 63;
    int p0 = blockIdx.x * 64 + w * 16;
    int lr = l & 15, lk = (l >> 4) * 8;
    f32x4 zero = {0.f, 0.f, 0.f, 0.f};
    f32x4 acc[3] = {zero, zero, zero};
    const ushort* hrow = hidden + (size_t)(p0 + lr) * HIDC + lk;
#pragma unroll 4
    for (int k0 = 0; k0 < 16; ++k0) {
        bf16x8 a = *(const bf16x8*)(hrow + k0 * 32);
#pragma unroll
        for (int ni = 0; ni < 3; ++ni) {
            bf16x8 bb = *(const bf16x8*)&W2[(ni * 16 + lr) * 520 + k0 * 32 + lk];
            acc[ni] = __builtin_amdgcn_mfma_f32_16x16x32_bf16(a, bb, acc[ni], 0, 0, 0);
        }
    }
    int lr4 = (l >> 4) * 4;
#pragma unroll
    for (int ni = 0; ni < 3; ++ni) {
        int m = ni * 16 + lr;
        float bias = (m < 9) ? cb[m] : ((m < 45) ? rb[m - 9] : 0.f);
#pragma unroll
        for (int r = 0; r < 4; ++r) {
            int p = p0 + lr4 + r;
            g[(size_t)p * 48 + m] = acc[ni][r] + bias;
        }
    }
}

// ---------- 6: proposal math ----------
__global__ void proposals(const float* __restrict__ g, float* __restrict__ out) {
    int i = blockIdx.x * 256 + threadIdx.x;
    if (i >= NPIX * 9) return;
    int p = i / 9, a = i - p * 9;
    int y = (p >> 5) & 31, x = p & 31;
    int si = a / 3, ri = a - si * 3;
    float hA = 2.f * (float)(si + 1);
    float wA = (float)((si + 1) * (ri + 1));

    const float* gp = g + (size_t)p * 48;
    float conf = gp[a];
    float o0 = gp[9 + a * 4 + 0];
    float o1 = gp[9 + a * 4 + 1];
    float o2 = gp[9 + a * 4 + 2];
    float o3 = gp[9 + a * 4 + 3];

    float cx = x + 0.5f, cy = y + 0.5f;
    float x1 = fminf(fmaxf(cx - wA * 0.5f, 0.f), 32.f);
    float y1 = fminf(fmaxf(cy - hA * 0.5f, 0.f), 32.f);
    float x2 = fminf(fmaxf(cx + wA * 0.5f, 0.f), 32.f);
    float y2 = fminf(fmaxf(cy + hA * 0.5f, 0.f), 32.f);
    float aw = x2 - x1, ah = y2 - y1;
    float acx = x1 + aw * 0.5f, acy = y1 + ah * 0.5f;
    float pcx = acx + o0 * aw, pcy = acy + o1 * ah;
    float pw = aw * expf(o2), ph = ah * expf(o3);
    float s = 1.f / (1.f + expf(-conf));

    float* o = out + (size_t)i * 5;
    o[0] = s;
    o[1] = (pcx - pw * 0.5f) * 32.f;
    o[2] = (pcy - ph * 0.5f) * 32.f;
    o[3] = (pcx + pw * 0.5f) * 32.f;
    o[4] = (pcy + ph * 0.5f) * 32.f;
}

extern "C" void kernel_launch(void* const* d_in, const int* in_sizes, int n_in,
                              void* d_out, int out_size, void* d_ws, size_t ws_size,
                              hipStream_t stream) {
    const float* x  = (const float*)d_in[0];
    const float* hw = (const float*)d_in[1];
    const float* hb = (const float*)d_in[2];
    const float* cw = (const float*)d_in[3];
    const float* cb = (const float*)d_in[4];
    const float* rw = (const float*)d_in[5];
    const float* rb = (const float*)d_in[6];
    float* out = (float*)d_out;

    char* ws = (char*)d_ws;
    ushort* xp     = (ushort*)(ws);                 // 8*34*34*2048*2  = 37,879,808
    ushort* wpk    = (ushort*)(ws + 37879808);      // 9*512*2048*2   = 18,874,368
    ushort* hidden = (ushort*)(ws + 56754176);      // 8192*512*2     =  8,388,608
    ushort* w2b    = (ushort*)(ws + 65142784);      // 48*512*2       =     49,152
    float*  g      = (float*)(ws + 65191936);       // 8192*48*4      =  1,572,864

    hipLaunchKernelGGL(zero_ws, dim3(2048), dim3(256), 0, stream,
                       (uint4*)xp, 37879808 / 16);
    hipLaunchKernelGGL(pack_x, dim3(16, 32, 8), dim3(256), 0, stream, x, xp);
    hipLaunchKernelGGL(pack_w, dim3(512), dim3(256), 0, stream, hw, wpk);
    hipLaunchKernelGGL(pack_w2, dim3(96), dim3(256), 0, stream, cw, rw, w2b);
    hipLaunchKernelGGL(conv_gemm, dim3(256), dim3(256), 0, stream, xp, wpk, hb, hidden);
    hipLaunchKernelGGL(gemm2, dim3(128), dim3(256), 0, stream, hidden, w2b, cb, rb, g);
    hipLaunchKernelGGL(proposals, dim3(288), dim3(256), 0, stream, g, out);
}

// Round 4
// 236.945 us; speedup vs baseline: 1.6664x; 1.5406x over previous
//
#include <hip/hip_runtime.h>
#include <hip/hip_bf16.h>

typedef __attribute__((ext_vector_type(8))) short bf16x8;
typedef __attribute__((ext_vector_type(4))) float f32x4;

#define NPIX 8192      // 8 * 32 * 32
#define HIDC 512
#define CIN  2048

// ---------- helpers ----------
__device__ __forceinline__ ushort f2b(float f) {
    union { float f; unsigned u; } v; v.f = f;
    unsigned r = v.u + 0x7fffu + ((v.u >> 16) & 1u);   // RNE
    return (ushort)(r >> 16);
}

__device__ __forceinline__ void gload16(const void* g, void* l) {
    __builtin_amdgcn_global_load_lds(
        (const __attribute__((address_space(1))) void*)g,
        (__attribute__((address_space(3))) void*)l, 16, 0, 0);
}

// ---------- 0: zero padded input buffer ----------
__global__ void zero_ws(uint4* __restrict__ p, int n16) {
    int i = blockIdx.x * blockDim.x + threadIdx.x;
    int stride = gridDim.x * blockDim.x;
    uint4 z = {0u, 0u, 0u, 0u};
    for (; i < n16; i += stride) p[i] = z;
}

// ---------- 1: NCHW fp32 -> padded NHWC bf16  xp[b][y+1][x+1][c] ----------
__global__ void pack_x(const float* __restrict__ x, ushort* __restrict__ xp) {
    __shared__ float tile[64][65];
    int b  = blockIdx.z;
    int c0 = blockIdx.y * 64;
    int p0 = blockIdx.x * 64;
    int t = threadIdx.x;
    int tx = t & 63, ty = t >> 6;
    const float* src = x + ((size_t)b * CIN + c0) * 1024 + p0;
    for (int i = ty; i < 64; i += 4)
        tile[i][tx] = src[(size_t)i * 1024 + tx];
    __syncthreads();
    int ci = t & 63, pj = t >> 6;
    for (int j = pj; j < 64; j += 4) {
        int p = p0 + j;
        int y = p >> 5, xx = p & 31;
        ushort* dst = xp + (((size_t)b * 34 + y + 1) * 34 + (xx + 1)) * CIN + c0;
        dst[ci] = f2b(tile[ci][j]);
    }
}

// ---------- 2: w[n][c][ky][kx] fp32 -> wpk[tap][n][c] bf16 ----------
__global__ void pack_w(const float* __restrict__ hw, ushort* __restrict__ wpk) {
    __shared__ float ld[512 * 9];
    int n = blockIdx.x;
    int t = threadIdx.x;
    const float* src = hw + (size_t)n * (CIN * 9);
    for (int cc0 = 0; cc0 < CIN; cc0 += 512) {
        for (int i = t; i < 4608; i += 256) ld[i] = src[(size_t)cc0 * 9 + i];
        __syncthreads();
        for (int t9 = 0; t9 < 9; ++t9)
            for (int idx = t; idx < 512; idx += 256)
                wpk[((size_t)(t9 * 512 + n)) * CIN + cc0 + idx] = f2b(ld[idx * 9 + t9]);
        __syncthreads();
    }
}

// ---------- 3: conf_w/reg_w -> w2b[48][512] bf16 (rows 45..47 zero) ----------
__global__ void pack_w2(const float* __restrict__ cw, const float* __restrict__ rw,
                        ushort* __restrict__ w2b) {
    int i = blockIdx.x * 256 + threadIdx.x;
    if (i >= 48 * 512) return;
    int m = i >> 9, c = i & 511;
    float v = 0.f;
    if (m < 9) v = cw[m * 512 + c];
    else if (m < 45) v = rw[(m - 9) * 512 + c];
    w2b[i] = f2b(v);
}

// ======== conv as implicit GEMM: shared body pieces ========
// LDS slot swizzle: slot(r,kc) = (r*4+kc) ^ ((r>>1)&7); staging dest linear,
// source (r,kc) permuted with same XOR; read side applies XOR. Conflict-free.

// ---------- 4a: split-K x3 version -> fp32 partials pp[3][8192][512] ----------
#define KSTEPS_SPLIT 192   // 3 taps * 64

__launch_bounds__(256, 3)
__global__ void conv_gemm_splitk(const ushort* __restrict__ xp, const ushort* __restrict__ wpk,
                                 float* __restrict__ pp) {
    __shared__ __align__(16) ushort A0[128 * 32];
    __shared__ __align__(16) ushort B0[128 * 32];
    __shared__ __align__(16) ushort A1[128 * 32];
    __shared__ __align__(16) ushort B1[128 * 32];

    int t = threadIdx.x;

    // 768 blocks on 8 XCDs (round-robin by hw): xcd = orig&7.
    // Per XCD: 96 slots = 32 (pb,nb) pairs x 3 k-splits -> A/B panels and
    // partial tiles of the same pair dedup in that XCD's L2.
    int orig = blockIdx.x;
    int xcd  = orig & 7;
    int slot = orig >> 3;          // 0..95
    int pairLocal = slot & 31;
    int ks   = slot >> 5;          // 0..2  (tap triple)
    int pair = (xcd << 5) + pairLocal;   // 0..255
    int nb = pair & 3;
    int pb = pair >> 2;
    int n0   = nb * 128;
    int pix0 = pb * 128;

    int w = t >> 6, l = t & 63;
    int wr = w >> 1, wc = w & 1;

    int u  = t ^ ((t >> 3) & 7);
    int rA = u >> 2;
    int kA = (u & 3) * 8;

    int p1 = pix0 + rA, p2 = p1 + 64;
    int b   = p1 >> 10;
    int py1 = (p1 >> 5) & 31, px1 = p1 & 31;
    int py2 = (p2 >> 5) & 31, px2 = p2 & 31;

    size_t aBase1 = ((size_t)b * 34 + py1) * 34 + px1;
    size_t aBase2 = ((size_t)b * 34 + py2) * 34 + px2;

    f32x4 zero = {0.f, 0.f, 0.f, 0.f};
    f32x4 acc[4][4];
#pragma unroll
    for (int i = 0; i < 4; ++i)
#pragma unroll
        for (int j = 0; j < 4; ++j) acc[i][j] = zero;

    int lr = l & 15;
    int kc = l >> 4;
    int sw = ((lr * 4 + kc) ^ ((lr >> 1) & 7)) * 16;

    int tap0 = ks * 3;

    auto stage = [&](int kk, ushort* As, ushort* Bs) {
        int tap = tap0 + (kk >> 6);
        int c0 = (kk & 63) << 5;
        int dy = tap / 3, dx = tap - dy * 3;
        size_t aoff = (size_t)(dy * 34 + dx) * CIN + kA + c0;
        gload16(xp + aBase1 * CIN + aoff, (char*)As + t * 16);
        gload16(xp + aBase2 * CIN + aoff, (char*)As + 4096 + t * 16);
        const ushort* bp = wpk + ((size_t)(tap * 512) + n0 + rA) * CIN + kA + c0;
        gload16(bp, (char*)Bs + t * 16);
        gload16(bp + (size_t)64 * CIN, (char*)Bs + 4096 + t * 16);
    };

    auto compute = [&](const ushort* As, const ushort* Bs) {
        const char* ab = (const char*)As + wr * 4096 + sw;
        const char* bb = (const char*)Bs + wc * 4096 + sw;
        bf16x8 af[4], bfr[4];
#pragma unroll
        for (int mi = 0; mi < 4; ++mi)
            af[mi] = *(const bf16x8*)(ab + mi * 1024);
#pragma unroll
        for (int ni = 0; ni < 4; ++ni)
            bfr[ni] = *(const bf16x8*)(bb + ni * 1024);
#pragma unroll
        for (int mi = 0; mi < 4; ++mi)
#pragma unroll
            for (int ni = 0; ni < 4; ++ni)
                acc[mi][ni] = __builtin_amdgcn_mfma_f32_16x16x32_bf16(
                    af[mi], bfr[ni], acc[mi][ni], 0, 0, 0);
    };

    stage(0, A0, B0);
    __syncthreads();
    for (int kk = 0; kk < KSTEPS_SPLIT; kk += 2) {
        if (kk + 1 < KSTEPS_SPLIT) stage(kk + 1, A1, B1);
        compute(A0, B0);
        __syncthreads();
        if (kk + 2 < KSTEPS_SPLIT) stage(kk + 2, A0, B0);
        compute(A1, B1);
        __syncthreads();
    }

    float* dst = pp + (size_t)ks * NPIX * HIDC;
    int lr4 = (l >> 4) * 4;
#pragma unroll
    for (int mi = 0; mi < 4; ++mi) {
#pragma unroll
        for (int ni = 0; ni < 4; ++ni) {
            int col = n0 + wc * 64 + ni * 16 + lr;
#pragma unroll
            for (int r = 0; r < 4; ++r) {
                int row = pix0 + wr * 64 + mi * 16 + lr4 + r;
                dst[(size_t)row * HIDC + col] = acc[mi][ni][r];
            }
        }
    }
}

// ---------- 4b: reduce partials + bias + relu -> hidden bf16 ----------
__global__ void reduce_bias_relu(const float* __restrict__ pp, const float* __restrict__ hb,
                                 ushort* __restrict__ hidden) {
    int i = blockIdx.x * 256 + threadIdx.x;          // over 4M/4 float4 groups
    const float4* p0 = (const float4*)pp;
    const float4* p1 = p0 + (size_t)NPIX * HIDC / 4;
    const float4* p2 = p1 + (size_t)NPIX * HIDC / 4;
    float4 a = p0[i], b = p1[i], c = p2[i];
    int col4 = (i & 127) * 4;
    const float4 bias = *(const float4*)&hb[col4];
    ushort4 r;
    float v0 = a.x + b.x + c.x + bias.x; r.x = f2b(v0 > 0.f ? v0 : 0.f);
    float v1 = a.y + b.y + c.y + bias.y; r.y = f2b(v1 > 0.f ? v1 : 0.f);
    float v2 = a.z + b.z + c.z + bias.z; r.z = f2b(v2 > 0.f ? v2 : 0.f);
    float v3 = a.w + b.w + c.w + bias.w; r.w = f2b(v3 > 0.f ? v3 : 0.f);
    *(ushort4*)&hidden[(size_t)i * 4] = r;
}

// ---------- 4c: fallback single-pass conv (round-3 kernel, kept verbatim) ----------
#define NKSTEP 576

__launch_bounds__(256, 1)
__global__ void conv_gemm(const ushort* __restrict__ xp, const ushort* __restrict__ wpk,
                          const float* __restrict__ hb, ushort* __restrict__ hidden) {
    __shared__ __align__(16) ushort A0[128 * 32];
    __shared__ __align__(16) ushort B0[128 * 32];
    __shared__ __align__(16) ushort A1[128 * 32];
    __shared__ __align__(16) ushort B1[128 * 32];

    int t = threadIdx.x;
    int orig = blockIdx.x;
    int xcd = orig & 7;
    int ix  = orig >> 3;
    int nb  = ix & 3;
    int pb  = (xcd << 3) + (ix >> 2);
    int n0   = nb * 128;
    int pix0 = pb * 128;

    int w = t >> 6, l = t & 63;
    int wr = w >> 1, wc = w & 1;

    int u  = t ^ ((t >> 3) & 7);
    int rA = u >> 2;
    int kA = (u & 3) * 8;

    int p1 = pix0 + rA, p2 = p1 + 64;
    int b   = p1 >> 10;
    int py1 = (p1 >> 5) & 31, px1 = p1 & 31;
    int py2 = (p2 >> 5) & 31, px2 = p2 & 31;

    size_t aBase1 = ((size_t)b * 34 + py1) * 34 + px1;
    size_t aBase2 = ((size_t)b * 34 + py2) * 34 + px2;

    f32x4 zero = {0.f, 0.f, 0.f, 0.f};
    f32x4 acc[4][4];
#pragma unroll
    for (int i = 0; i < 4; ++i)
#pragma unroll
        for (int j = 0; j < 4; ++j) acc[i][j] = zero;

    int lr = l & 15;
    int kc = l >> 4;
    int sw = ((lr * 4 + kc) ^ ((lr >> 1) & 7)) * 16;

    auto stage = [&](int kk, ushort* As, ushort* Bs) {
        int tap = kk >> 6;
        int c0 = (kk & 63) << 5;
        int dy = tap / 3, dx = tap - dy * 3;
        size_t aoff = (size_t)(dy * 34 + dx) * CIN + kA + c0;
        gload16(xp + aBase1 * CIN + aoff, (char*)As + t * 16);
        gload16(xp + aBase2 * CIN + aoff, (char*)As + 4096 + t * 16);
        const ushort* bp = wpk + ((size_t)(tap * 512) + n0 + rA) * CIN + kA + c0;
        gload16(bp, (char*)Bs + t * 16);
        gload16(bp + (size_t)64 * CIN, (char*)Bs + 4096 + t * 16);
    };

    auto compute = [&](const ushort* As, const ushort* Bs) {
        const char* ab = (const char*)As + wr * 4096 + sw;
        const char* bb = (const char*)Bs + wc * 4096 + sw;
        bf16x8 af[4], bfr[4];
#pragma unroll
        for (int mi = 0; mi < 4; ++mi)
            af[mi] = *(const bf16x8*)(ab + mi * 1024);
#pragma unroll
        for (int ni = 0; ni < 4; ++ni)
            bfr[ni] = *(const bf16x8*)(bb + ni * 1024);
#pragma unroll
        for (int mi = 0; mi < 4; ++mi)
#pragma unroll
            for (int ni = 0; ni < 4; ++ni)
                acc[mi][ni] = __builtin_amdgcn_mfma_f32_16x16x32_bf16(
                    af[mi], bfr[ni], acc[mi][ni], 0, 0, 0);
    };

    stage(0, A0, B0);
    __syncthreads();
    for (int kk = 0; kk < NKSTEP; kk += 2) {
        if (kk + 1 < NKSTEP) stage(kk + 1, A1, B1);
        compute(A0, B0);
        __syncthreads();
        if (kk + 2 < NKSTEP) stage(kk + 2, A0, B0);
        compute(A1, B1);
        __syncthreads();
    }

    int lr4 = (l >> 4) * 4;
#pragma unroll
    for (int mi = 0; mi < 4; ++mi) {
#pragma unroll
        for (int ni = 0; ni < 4; ++ni) {
            int col = n0 + wc * 64 + ni * 16 + lr;
            float bias = hb[col];
#pragma unroll
            for (int r = 0; r < 4; ++r) {
                int row = pix0 + wr * 64 + mi * 16 + lr4 + r;
                float v = acc[mi][ni][r] + bias;
                v = v > 0.f ? v : 0.f;
                hidden[(size_t)row * HIDC + col] = f2b(v);
            }
        }
    }
}

// ---------- 5: 1x1 convs as GEMM (N=48 incl pad), bias -> g fp32 [8192][48] ----------
__launch_bounds__(256)
__global__ void gemm2(const ushort* __restrict__ hidden, const ushort* __restrict__ w2b,
                      const float* __restrict__ cb, const float* __restrict__ rb,
                      float* __restrict__ g) {
    __shared__ __align__(16) ushort W2[48 * 520];
    int t = threadIdx.x;
    const unsigned* src = (const unsigned*)w2b;
    unsigned* dstW = (unsigned*)&W2[0];
    for (int i = t; i < 12288; i += 256) {
        int m = i >> 8, c2 = i & 255;
        dstW[m * 260 + c2] = src[i];
    }
    __syncthreads();
    int w = t >> 6, l = t & 63;
    int p0 = blockIdx.x * 64 + w * 16;
    int lr = l & 15, lk = (l >> 4) * 8;
    f32x4 zero = {0.f, 0.f, 0.f, 0.f};
    f32x4 acc[3] = {zero, zero, zero};
    const ushort* hrow = hidden + (size_t)(p0 + lr) * HIDC + lk;
#pragma unroll 4
    for (int k0 = 0; k0 < 16; ++k0) {
        bf16x8 a = *(const bf16x8*)(hrow + k0 * 32);
#pragma unroll
        for (int ni = 0; ni < 3; ++ni) {
            bf16x8 bb = *(const bf16x8*)&W2[(ni * 16 + lr) * 520 + k0 * 32 + lk];
            acc[ni] = __builtin_amdgcn_mfma_f32_16x16x32_bf16(a, bb, acc[ni], 0, 0, 0);
        }
    }
    int lr4 = (l >> 4) * 4;
#pragma unroll
    for (int ni = 0; ni < 3; ++ni) {
        int m = ni * 16 + lr;
        float bias = (m < 9) ? cb[m] : ((m < 45) ? rb[m - 9] : 0.f);
#pragma unroll
        for (int r = 0; r < 4; ++r) {
            int p = p0 + lr4 + r;
            g[(size_t)p * 48 + m] = acc[ni][r] + bias;
        }
    }
}

// ---------- 6: proposal math ----------
__global__ void proposals(const float* __restrict__ g, float* __restrict__ out) {
    int i = blockIdx.x * 256 + threadIdx.x;
    if (i >= NPIX * 9) return;
    int p = i / 9, a = i - p * 9;
    int y = (p >> 5) & 31, x = p & 31;
    int si = a / 3, ri = a - si * 3;
    float hA = 2.f * (float)(si + 1);
    float wA = (float)((si + 1) * (ri + 1));

    const float* gp = g + (size_t)p * 48;
    float conf = gp[a];
    float o0 = gp[9 + a * 4 + 0];
    float o1 = gp[9 + a * 4 + 1];
    float o2 = gp[9 + a * 4 + 2];
    float o3 = gp[9 + a * 4 + 3];

    float cx = x + 0.5f, cy = y + 0.5f;
    float x1 = fminf(fmaxf(cx - wA * 0.5f, 0.f), 32.f);
    float y1 = fminf(fmaxf(cy - hA * 0.5f, 0.f), 32.f);
    float x2 = fminf(fmaxf(cx + wA * 0.5f, 0.f), 32.f);
    float y2 = fminf(fmaxf(cy + hA * 0.5f, 0.f), 32.f);
    float aw = x2 - x1, ah = y2 - y1;
    float acx = x1 + aw * 0.5f, acy = y1 + ah * 0.5f;
    float pcx = acx + o0 * aw, pcy = acy + o1 * ah;
    float pw = aw * expf(o2), ph = ah * expf(o3);
    float s = 1.f / (1.f + expf(-conf));

    float* o = out + (size_t)i * 5;
    o[0] = s;
    o[1] = (pcx - pw * 0.5f) * 32.f;
    o[2] = (pcy - ph * 0.5f) * 32.f;
    o[3] = (pcx + pw * 0.5f) * 32.f;
    o[4] = (pcy + ph * 0.5f) * 32.f;
}

extern "C" void kernel_launch(void* const* d_in, const int* in_sizes, int n_in,
                              void* d_out, int out_size, void* d_ws, size_t ws_size,
                              hipStream_t stream) {
    const float* x  = (const float*)d_in[0];
    const float* hw = (const float*)d_in[1];
    const float* hb = (const float*)d_in[2];
    const float* cw = (const float*)d_in[3];
    const float* cb = (const float*)d_in[4];
    const float* rw = (const float*)d_in[5];
    const float* rb = (const float*)d_in[6];
    float* out = (float*)d_out;

    char* ws = (char*)d_ws;
    ushort* xp     = (ushort*)(ws);                 // 8*34*34*2048*2  = 37,879,808
    ushort* wpk    = (ushort*)(ws + 37879808);      // 9*512*2048*2   = 18,874,368
    ushort* hidden = (ushort*)(ws + 56754176);      // 8192*512*2     =  8,388,608
    ushort* w2b    = (ushort*)(ws + 65142784);      // 48*512*2       =     49,152
    float*  g      = (float*)(ws + 65191936);       // 8192*48*4      =  1,572,864
    float*  pp     = (float*)(ws + 66764800);       // 3*8192*512*4   = 50,331,648
    const size_t WS_NEED_SPLITK = 66764800 + 50331648;   // 117,096,448

    hipLaunchKernelGGL(zero_ws, dim3(2048), dim3(256), 0, stream,
                       (uint4*)xp, 37879808 / 16);
    hipLaunchKernelGGL(pack_x, dim3(16, 32, 8), dim3(256), 0, stream, x, xp);
    hipLaunchKernelGGL(pack_w, dim3(512), dim3(256), 0, stream, hw, wpk);
    hipLaunchKernelGGL(pack_w2, dim3(96), dim3(256), 0, stream, cw, rw, w2b);
    if (ws_size >= WS_NEED_SPLITK) {
        hipLaunchKernelGGL(conv_gemm_splitk, dim3(768), dim3(256), 0, stream, xp, wpk, pp);
        hipLaunchKernelGGL(reduce_bias_relu, dim3(4096), dim3(256), 0, stream, pp, hb, hidden);
    } else {
        hipLaunchKernelGGL(conv_gemm, dim3(256), dim3(256), 0, stream, xp, wpk, hb, hidden);
    }
    hipLaunchKernelGGL(gemm2, dim3(128), dim3(256), 0, stream, hidden, w2b, cb, rb, g);
    hipLaunchKernelGGL(proposals, dim3(288), dim3(256), 0, stream, g, out);
}